// Round 1
// baseline (434.548 us; speedup 1.0000x reference)
//
#include <hip/hip_runtime.h>

// Sparsemax over rows: x [16384,4096] fp32 -> out same shape.
// Block-per-row (256 thr, 16 vals/thread) at MAX occupancy:
// __launch_bounds__(256,8) -> ~50 VGPR -> 8 blocks/CU = 32 waves/CU.
//
// R5 structure: ONE barrier per row (was 3).
//  - Candidate bound is WAVE-local (wavemax-1), not row-global: the union of
//    per-wave candidate sets still contains the support, since
//    support ⊆ {x > rowmax-1} ⊆ ∪_w {x > wavemax_w - 1}. This removes the
//    rowmax-reduction barrier.
//  - Compaction via ballot+popc into a private per-wave LDS segment (no LDS
//    atomics, no divergent serialization).
//  - After the single barrier, EVERY wave redundantly runs the in-register
//    Michelot on the merged candidate set (typ. ~55 cands ≤ 64 lanes), so no
//    tau-broadcast barrier and no serial-wave-0 bubble. All waves compute a
//    bit-identical tau.
//  - Pathological fallback (>128 cands in one wave) keeps the barriered
//    binary search; the branch is block-uniform (decided from post-barrier
//    LDS counts) so __syncthreads inside it is legal.

constexpr int COLS = 4096;
constexpr int TPB  = 256;
constexpr int NWV  = TPB / 64;   // 4 waves
constexpr int CAPW = 128;        // per-wave candidate capacity

using f32x4 = __attribute__((ext_vector_type(4))) float;

__device__ __forceinline__ float wred_sum(float v) {
    #pragma unroll
    for (int m = 32; m; m >>= 1) v += __shfl_xor(v, m, 64);
    return v;
}
__device__ __forceinline__ float wred_max(float v) {
    #pragma unroll
    for (int m = 32; m; m >>= 1) v = fmaxf(v, __shfl_xor(v, m, 64));
    return v;
}

__global__ __launch_bounds__(TPB, 8) void sparsemax_kernel(const float* __restrict__ x,
                                                           float* __restrict__ out) {
    const int row  = blockIdx.x;
    const int tid  = threadIdx.x;
    const int lane = tid & 63;
    const int wv   = tid >> 6;

    const f32x4* __restrict__ xr  = reinterpret_cast<const f32x4*>(x + (size_t)row * COLS);
    f32x4* __restrict__       orr = reinterpret_cast<f32x4*>(out + (size_t)row * COLS);

    // 4 independent coalesced 16B loads -> 16 floats/thread.
    f32x4 q0 = xr[tid], q1 = xr[tid + TPB], q2 = xr[tid + 2 * TPB], q3 = xr[tid + 3 * TPB];
    float v[16] = {q0.x, q0.y, q0.z, q0.w, q1.x, q1.y, q1.z, q1.w,
                   q2.x, q2.y, q2.z, q2.w, q3.x, q3.y, q3.z, q3.w};
    #pragma unroll
    for (int j = 0; j < 16; ++j) asm volatile("" : "+v"(v[j]));  // keep register-resident

    __shared__ float cand[NWV][CAPW];
    __shared__ float redm[NWV];
    __shared__ int   redc[NWV];
    __shared__ float reds[NWV], redcf[NWV];   // fallback reductions

    // ---- wave-local max (no barrier needed) ----
    float mx = v[0];
    #pragma unroll
    for (int j = 1; j < 16; ++j) mx = fmaxf(mx, v[j]);
    mx = wred_max(mx);                 // uniform within wave
    const float lbw = mx - 1.0f;       // wave-local candidate bound

    // ---- ballot compaction into this wave's private LDS segment ----
    const unsigned long long below = (1ull << lane) - 1ull;
    int base = 0;
    #pragma unroll
    for (int j = 0; j < 16; ++j) {
        const bool p = v[j] > lbw;
        const unsigned long long m = __ballot(p);
        if (p) {
            const int pos = base + __popcll(m & below);
            if (pos < CAPW) cand[wv][pos] = v[j];
        }
        base += __popcll(m);
    }
    if (lane == 0) { redc[wv] = base; redm[wv] = mx; }

    __syncthreads();   // the ONE barrier in the common path

    const int c0 = redc[0], c1 = redc[1], c2 = redc[2], c3 = redc[3];
    const bool ovf = (c0 > CAPW) | (c1 > CAPW) | (c2 > CAPW) | (c3 > CAPW);

    float tau;
    if (!ovf) {
        const int p1 = c0, p2 = p1 + c1, p3 = p2 + c2, nc = p3 + c3;   // nc >= 4
        float t;
        if (nc <= 64) {
            // One LDS read/lane from the virtual concat; Michelot in registers.
            int seg, off;
            if      (lane < p1) { seg = 0; off = lane; }
            else if (lane < p2) { seg = 1; off = lane - p1; }
            else if (lane < p3) { seg = 2; off = lane - p2; }
            else                { seg = 3; off = lane - p3; }   // off <= 63 < CAPW, safe
            const float cv = (lane < nc) ? cand[seg][off] : 0.f;
            const float s0 = wred_sum(cv);
            t = (s0 - 1.f) / (float)nc;                 // tau_0 <= tau*, ascends
            const float cvm = (lane < nc) ? cv : -3.0e38f;
            for (int it = 0; it < 66; ++it) {
                float si = (cvm > t) ? cvm : 0.f;
                float ci = (cvm > t) ? 1.f : 0.f;
                si = wred_sum(si); ci = wred_sum(ci);   // ci >= 1 (wave max > t)
                const float nt = (si - 1.f) / ci;
                if (nt == t) break;                     // set stabilized -> exact
                t = nt;
            }
        } else {
            // 64 < nc <= 4*CAPW: strided Michelot over the virtual concat.
            float s = 0.f, cnt = 0.f;
            for (int j = lane; j < nc; j += 64) {
                int seg, off;
                if      (j < p1) { seg = 0; off = j; }
                else if (j < p2) { seg = 1; off = j - p1; }
                else if (j < p3) { seg = 2; off = j - p2; }
                else             { seg = 3; off = j - p3; }
                s += cand[seg][off]; cnt += 1.f;
            }
            s = wred_sum(s); cnt = wred_sum(cnt);
            t = (s - 1.f) / cnt;
            for (int it = 0; it < 4 * CAPW + 2; ++it) {
                float si = 0.f, ci = 0.f;
                for (int j = lane; j < nc; j += 64) {
                    int seg, off;
                    if      (j < p1) { seg = 0; off = j; }
                    else if (j < p2) { seg = 1; off = j - p1; }
                    else if (j < p3) { seg = 2; off = j - p2; }
                    else             { seg = 3; off = j - p3; }
                    const float cv = cand[seg][off];
                    if (cv > t) { si += cv; ci += 1.f; }
                }
                si = wred_sum(si); ci = wred_sum(ci);
                const float nt = (si - 1.f) / ci;
                if (nt == t) break;
                t = nt;
            }
        }
        tau = t;
    } else {
        // Pathological fallback (>128 candidates within 1.0 of a wave max):
        // block binary search over registers, then exact final step.
        // Block-uniform branch -> barriers legal.
        const float rowmax = fmaxf(fmaxf(redm[0], redm[1]), fmaxf(redm[2], redm[3]));
        float lo = rowmax - 1.0f, hi = rowmax;
        for (int it = 0; it < 40; ++it) {
            const float mid = 0.5f * (lo + hi);
            float s = 0.f;
            #pragma unroll
            for (int j = 0; j < 16; ++j) s += fmaxf(v[j] - mid, 0.f);
            s = wred_sum(s);
            if (lane == 0) reds[wv] = s;
            __syncthreads();
            s = reds[0] + reds[1] + reds[2] + reds[3];
            __syncthreads();
            if (s > 1.f) lo = mid; else hi = mid;
        }
        float s = 0.f, cnt = 0.f;
        #pragma unroll
        for (int j = 0; j < 16; ++j) if (v[j] > lo) { s += v[j]; cnt += 1.f; }
        s = wred_sum(s); cnt = wred_sum(cnt);
        if (lane == 0) { reds[wv] = s; redcf[wv] = cnt; }
        __syncthreads();
        s   = reds[0] + reds[1] + reds[2] + reds[3];
        cnt = redcf[0] + redcf[1] + redcf[2] + redcf[3];
        tau = (s - 1.f) / cnt;
    }

    // ---- epilogue: out = max(x - tau, 0), plain dwordx4 stores ----
    f32x4 r0, r1, r2, r3;
    r0.x = fmaxf(v[0]  - tau, 0.f); r0.y = fmaxf(v[1]  - tau, 0.f);
    r0.z = fmaxf(v[2]  - tau, 0.f); r0.w = fmaxf(v[3]  - tau, 0.f);
    r1.x = fmaxf(v[4]  - tau, 0.f); r1.y = fmaxf(v[5]  - tau, 0.f);
    r1.z = fmaxf(v[6]  - tau, 0.f); r1.w = fmaxf(v[7]  - tau, 0.f);
    r2.x = fmaxf(v[8]  - tau, 0.f); r2.y = fmaxf(v[9]  - tau, 0.f);
    r2.z = fmaxf(v[10] - tau, 0.f); r2.w = fmaxf(v[11] - tau, 0.f);
    r3.x = fmaxf(v[12] - tau, 0.f); r3.y = fmaxf(v[13] - tau, 0.f);
    r3.z = fmaxf(v[14] - tau, 0.f); r3.w = fmaxf(v[15] - tau, 0.f);
    orr[tid]           = r0;
    orr[tid + TPB]     = r1;
    orr[tid + 2 * TPB] = r2;
    orr[tid + 3 * TPB] = r3;
}

extern "C" void kernel_launch(void* const* d_in, const int* in_sizes, int n_in,
                              void* d_out, int out_size, void* d_ws, size_t ws_size,
                              hipStream_t stream) {
    const float* x = (const float*)d_in[0];
    float*       o = (float*)d_out;
    const int rows = in_sizes[0] / COLS;   // 16384
    sparsemax_kernel<<<rows, TPB, 0, stream>>>(x, o);
}